// Round 1
// baseline (242.663 us; speedup 1.0000x reference)
//
#include <hip/hip_runtime.h>

#define BATCH   4096
#define IN_F    1024
#define OUT_F   1024
#define KF      8
#define KD      (2*IN_F*KF)   /* 16384 GEMM K-dim */
#define HALF_KD (IN_F*KF)     /* 8192 */

#define BM 128
#define BN 128
#define BK 64
#define KSPLIT 4
#define KCHUNK (KD/KSPLIT)    /* 4096 */

typedef short short8 __attribute__((ext_vector_type(8)));
typedef float f32x4  __attribute__((ext_vector_type(4)));

// bf16 round-to-nearest-even from f32 (bit pattern in ushort)
__device__ __forceinline__ unsigned short f2bf(float f) {
  union { float f; unsigned int u; } v; v.f = f;
  unsigned int u = v.u;
  unsigned int lsb = (u >> 16) & 1u;
  u += 0x7fffu + lsb;
  return (unsigned short)(u >> 16);
}

__device__ __forceinline__ void gload_lds16(const void* g, void* l) {
  __builtin_amdgcn_global_load_lds((const __attribute__((address_space(1))) void*)g,
                                   (__attribute__((address_space(3))) void*)l,
                                   16, 0, 0);
}

// ---------------- W conversion: [a | b] f32 -> bf16 [OUT_F][KD] ----------------
__global__ __launch_bounds__(256) void wconv_kernel(const float* __restrict__ a,
                                                    const float* __restrict__ b,
                                                    unsigned short* __restrict__ W) {
  size_t t = (size_t)blockIdx.x * 256 + threadIdx.x;
  size_t g = t * 8;                       // element index into W
  int o = (int)(g >> 14);                 // /16384
  int f = (int)(g & (KD - 1));
  const float* src = (f < HALF_KD) ? (a + (size_t)o * HALF_KD + f)
                                   : (b + (size_t)o * HALF_KD + (f - HALF_KD));
  float4 v0 = reinterpret_cast<const float4*>(src)[0];
  float4 v1 = reinterpret_cast<const float4*>(src)[1];
  union { unsigned short h[8]; int4 v; } u;
  u.h[0] = f2bf(v0.x); u.h[1] = f2bf(v0.y); u.h[2] = f2bf(v0.z); u.h[3] = f2bf(v0.w);
  u.h[4] = f2bf(v1.x); u.h[5] = f2bf(v1.y); u.h[6] = f2bf(v1.z); u.h[7] = f2bf(v1.w);
  *reinterpret_cast<int4*>(W + g) = u.v;
}

// ---------------- feature kernel: Xf[b, i*8+k] = sin(k x), +8192 -> cos ----------------
__global__ __launch_bounds__(256) void feat_kernel(const float* __restrict__ x,
                                                   unsigned short* __restrict__ Xf) {
  int idx = blockIdx.x * 256 + threadIdx.x;   // one per (b, i); exact multiple
  int bb = idx >> 10;
  int i  = idx & 1023;
  float xv = x[idx];
  float s1, c1;
  sincosf(xv, &s1, &c1);
  float sv[KF], cv[KF];
  sv[0] = 0.f; cv[0] = 1.f;
  sv[1] = s1;  cv[1] = c1;
#pragma unroll
  for (int k = 2; k < KF; ++k) {
    sv[k] = sv[k-1]*c1 + cv[k-1]*s1;
    cv[k] = cv[k-1]*c1 - sv[k-1]*s1;
  }
  union { unsigned short h[8]; int4 v; } us, uc;
#pragma unroll
  for (int k = 0; k < KF; ++k) { us.h[k] = f2bf(sv[k]); uc.h[k] = f2bf(cv[k]); }
  size_t base = (size_t)bb * KD + (size_t)i * KF;
  *reinterpret_cast<int4*>(Xf + base)           = us.v;
  *reinterpret_cast<int4*>(Xf + base + HALF_KD) = uc.v;
}

// ---------------- GEMM: C[M,N] += A[M,KD] * Bt[N,KD]^T over K-chunk ----------------
// m97-style: 128x128 tile, BK=64, 4 waves (2x2), each 64x64 via 4x4 frags of 16x16x32.
__global__ __launch_bounds__(256, 3) void gemm_kernel(const unsigned short* __restrict__ A,
                                                      const unsigned short* __restrict__ Bt,
                                                      float* __restrict__ C) {
  __shared__ unsigned short sA[BM * BK];
  __shared__ unsigned short sB[BN * BK];

  const int tid  = threadIdx.x;
  const int wid  = tid >> 6;
  const int lane = tid & 63;
  const int m0 = blockIdx.y * BM;
  const int n0 = blockIdx.x * BN;
  const int f_base = blockIdx.z * KCHUNK;
  const int wm = wid >> 1, wn = wid & 1;   // 2x2 wave grid, 64x64 each

  f32x4 acc[4][4] = {};

  // staging addressing: chunk c = wid*4 + j covers rows c*8 .. c*8+7, 64 k-elems
  const int srow = lane >> 3;              // row within 8-row chunk
  const int skel = (lane & 7) * 8;         // k element offset (16B granules)
  const unsigned short* Abase = A + (size_t)(m0 + wid*32 + srow) * KD + f_base + skel;
  const unsigned short* Bbase = Bt + (size_t)(n0 + wid*32 + srow) * KD + f_base + skel;
  unsigned short* sAdst = &sA[(wid*4) * 512];   // 512 elems = 1024 B per chunk
  unsigned short* sBdst = &sB[(wid*4) * 512];

  // fragment read addressing
  const unsigned short* sArow = &sA[(wm*64 + (lane & 15)) * BK + (lane >> 4) * 8];
  const unsigned short* sBrow = &sB[(wn*64 + (lane & 15)) * BK + (lane >> 4) * 8];

  for (int kt = 0; kt < KCHUNK; kt += BK) {
#pragma unroll
    for (int j = 0; j < 4; ++j)
      gload_lds16(Abase + (size_t)j * 8 * KD + kt, sAdst + j * 512);
#pragma unroll
    for (int j = 0; j < 4; ++j)
      gload_lds16(Bbase + (size_t)j * 8 * KD + kt, sBdst + j * 512);

    asm volatile("s_waitcnt vmcnt(0)" ::: "memory");
    __syncthreads();

#pragma unroll
    for (int ks = 0; ks < 2; ++ks) {
      short8 af[4], bf[4];
#pragma unroll
      for (int mi = 0; mi < 4; ++mi)
        af[mi] = *reinterpret_cast<const short8*>(sArow + mi * 16 * BK + ks * 32);
#pragma unroll
      for (int ni = 0; ni < 4; ++ni)
        bf[ni] = *reinterpret_cast<const short8*>(sBrow + ni * 16 * BK + ks * 32);
#pragma unroll
      for (int mi = 0; mi < 4; ++mi)
#pragma unroll
        for (int ni = 0; ni < 4; ++ni)
          acc[mi][ni] = __builtin_amdgcn_mfma_f32_16x16x32_bf16(af[mi], bf[ni], acc[mi][ni], 0, 0, 0);
    }
    __syncthreads();
  }

  // epilogue: accumulate K-chunks via device-scope f32 atomics (d_out pre-zeroed)
  const int crow0 = (lane >> 4) * 4;
  const int ccol  = lane & 15;
#pragma unroll
  for (int mi = 0; mi < 4; ++mi)
#pragma unroll
    for (int ni = 0; ni < 4; ++ni)
#pragma unroll
      for (int j = 0; j < 4; ++j) {
        int r = m0 + wm*64 + mi*16 + crow0 + j;
        int c = n0 + wn*64 + ni*16 + ccol;
        atomicAdd(&C[(size_t)r * OUT_F + c], acc[mi][ni][j]);
      }
}

// ---------------- fallback (no workspace): direct f32 evaluation ----------------
__global__ __launch_bounds__(256) void naive_kernel(const float* __restrict__ x,
                                                    const float* __restrict__ a,
                                                    const float* __restrict__ b,
                                                    float* __restrict__ y) {
  int o  = blockIdx.x * 256 + threadIdx.x;
  int bb = blockIdx.y;
  __shared__ float xs[IN_F];
  for (int i = threadIdx.x; i < IN_F; i += 256) xs[i] = x[(size_t)bb * IN_F + i];
  __syncthreads();
  float acc = 0.f;
  for (int i = 0; i < IN_F; ++i) {
    float s1, c1; sincosf(xs[i], &s1, &c1);
    float sk = 0.f, ck = 1.f;
    const float* ap = a + (size_t)o * HALF_KD + i * KF;
    const float* bp = b + (size_t)o * HALF_KD + i * KF;
#pragma unroll
    for (int k = 0; k < KF; ++k) {
      acc += sk * ap[k] + ck * bp[k];
      float sn = sk * c1 + ck * s1;
      ck = ck * c1 - sk * s1;
      sk = sn;
    }
  }
  y[(size_t)bb * OUT_F + o] = acc;
}

extern "C" void kernel_launch(void* const* d_in, const int* in_sizes, int n_in,
                              void* d_out, int out_size, void* d_ws, size_t ws_size,
                              hipStream_t stream) {
  (void)in_sizes; (void)n_in; (void)out_size;
  const float* x = (const float*)d_in[0];
  const float* a = (const float*)d_in[1];
  const float* b = (const float*)d_in[2];
  float* y = (float*)d_out;

  const size_t XF_BYTES = (size_t)BATCH * KD * sizeof(unsigned short);   // 128 MiB
  const size_t W_BYTES  = (size_t)OUT_F * KD * sizeof(unsigned short);   // 32 MiB

  if (ws_size >= XF_BYTES + W_BYTES) {
    unsigned short* Xf = (unsigned short*)d_ws;
    unsigned short* W  = (unsigned short*)((char*)d_ws + XF_BYTES);
    hipMemsetAsync(d_out, 0, (size_t)BATCH * OUT_F * sizeof(float), stream);
    wconv_kernel<<<(OUT_F * KD / 8) / 256, 256, 0, stream>>>(a, b, W);
    feat_kernel<<<(BATCH * IN_F) / 256, 256, 0, stream>>>(x, Xf);
    gemm_kernel<<<dim3(OUT_F / BN, BATCH / BM, KSPLIT), 256, 0, stream>>>(Xf, W, y);
  } else {
    naive_kernel<<<dim3(OUT_F / 256, BATCH), 256, 0, stream>>>(x, a, b, y);
  }
}

// Round 2
// 199.957 us; speedup vs baseline: 1.2136x; 1.2136x over previous
//
#include <hip/hip_runtime.h>

#define BATCH   4096
#define IN_F    1024
#define OUT_F   1024
#define KF      8
#define KD      (2*IN_F*KF)   /* 16384 GEMM K-dim */
#define HALF_KD (IN_F*KF)     /* 8192 */

#define BM 256
#define BN 256
#define BK 64
#define KSPLIT 4
#define KCHUNK (KD/KSPLIT)    /* 4096 */
#define NT (KCHUNK/BK)        /* 64 K-tiles per block */

typedef short short8 __attribute__((ext_vector_type(8)));
typedef float f32x4  __attribute__((ext_vector_type(4)));

// bf16 round-to-nearest-even from f32 (bit pattern in ushort)
__device__ __forceinline__ unsigned short f2bf(float f) {
  union { float f; unsigned int u; } v; v.f = f;
  unsigned int u = v.u;
  unsigned int lsb = (u >> 16) & 1u;
  u += 0x7fffu + lsb;
  return (unsigned short)(u >> 16);
}

__device__ __forceinline__ void gload_lds16(const void* g, void* l) {
  __builtin_amdgcn_global_load_lds((const __attribute__((address_space(1))) void*)g,
                                   (__attribute__((address_space(3))) void*)l,
                                   16, 0, 0);
}

// ---------------- W conversion: [a | b] f32 -> bf16 [OUT_F][KD] ----------------
__global__ __launch_bounds__(256) void wconv_kernel(const float* __restrict__ a,
                                                    const float* __restrict__ b,
                                                    unsigned short* __restrict__ W) {
  size_t t = (size_t)blockIdx.x * 256 + threadIdx.x;
  size_t g = t * 8;
  int o = (int)(g >> 14);
  int f = (int)(g & (KD - 1));
  const float* src = (f < HALF_KD) ? (a + (size_t)o * HALF_KD + f)
                                   : (b + (size_t)o * HALF_KD + (f - HALF_KD));
  float4 v0 = reinterpret_cast<const float4*>(src)[0];
  float4 v1 = reinterpret_cast<const float4*>(src)[1];
  union { unsigned short h[8]; int4 v; } u;
  u.h[0] = f2bf(v0.x); u.h[1] = f2bf(v0.y); u.h[2] = f2bf(v0.z); u.h[3] = f2bf(v0.w);
  u.h[4] = f2bf(v1.x); u.h[5] = f2bf(v1.y); u.h[6] = f2bf(v1.z); u.h[7] = f2bf(v1.w);
  *reinterpret_cast<int4*>(W + g) = u.v;
}

// ---------------- feature kernel: Xf[b, i*8+k] = sin(k x), +8192 -> cos ----------------
__global__ __launch_bounds__(256) void feat_kernel(const float* __restrict__ x,
                                                   unsigned short* __restrict__ Xf) {
  int idx = blockIdx.x * 256 + threadIdx.x;
  int bb = idx >> 10;
  int i  = idx & 1023;
  float xv = x[idx];
  float s1, c1;
  sincosf(xv, &s1, &c1);
  float sv[KF], cv[KF];
  sv[0] = 0.f; cv[0] = 1.f;
  sv[1] = s1;  cv[1] = c1;
#pragma unroll
  for (int k = 2; k < KF; ++k) {
    sv[k] = sv[k-1]*c1 + cv[k-1]*s1;
    cv[k] = cv[k-1]*c1 - sv[k-1]*s1;
  }
  union { unsigned short h[8]; int4 v; } us, uc;
#pragma unroll
  for (int k = 0; k < KF; ++k) { us.h[k] = f2bf(sv[k]); uc.h[k] = f2bf(cv[k]); }
  size_t base = (size_t)bb * KD + (size_t)i * KF;
  *reinterpret_cast<int4*>(Xf + base)           = us.v;
  *reinterpret_cast<int4*>(Xf + base + HALF_KD) = uc.v;
}

// ---------------- GEMM: 256x256 tile, 8-phase-style schedule, counted vmcnt ----------------
// 8 waves (2M x 4N), per-wave 128x64 output = acc[8][4]. 4 phases per K-tile
// (phase p = m-frags {2p,2p+1} x 4 nf x 2 ks = 16 MFMA). B-frags held in regs.
// LDS: double-buffered A,B tiles, 128 KiB. T2 XOR swizzle (granule ^= row&7)
// via pre-swizzled global source + swizzled ds_read. vmcnt(4)@p1, vmcnt(2)@p3.
__global__ __launch_bounds__(512, 2) void gemm_kernel(const unsigned short* __restrict__ A,
                                                      const unsigned short* __restrict__ Bt,
                                                      float* __restrict__ C) {
  __shared__ unsigned short sA[2][BM * BK];   // 32 KiB each
  __shared__ unsigned short sB[2][BN * BK];

  const int tid  = threadIdx.x;
  const int wid  = tid >> 6;
  const int lane = tid & 63;
  const int wm = wid >> 2, wn = wid & 3;

  // bijective XCD swizzle: 256 blocks % 8 XCDs == 0; 32 consecutive work items/XCD
  const int bid = blockIdx.x;
  const int s   = (bid & 7) * 32 + (bid >> 3);
  const int z   = s >> 6;          // K-split chunk 0..3
  const int mt  = s & 15;          // m-tile (fastest -> XCD shares B-panels)
  const int nt  = (s >> 4) & 3;    // n-tile
  const int m0  = mt * BM;
  const int n0  = nt * BN;
  const int fbase = z * KCHUNK;

  // ---- staging addressing (pre-swizzled global source, linear LDS dest) ----
  const int srow = wid * 8 + (lane >> 3);        // row within a 64-row group
  const int gsw  = (lane & 7) ^ (lane >> 3);     // swizzled 16B granule (involution)
  const unsigned short* pA = A  + (size_t)(m0 + srow) * KD + fbase + gsw * 8;
  const unsigned short* pB = Bt + (size_t)(n0 + srow) * KD + fbase + gsw * 8;
  const int ldst = wid * 512;                    // wave-uniform LDS elem offset in group

  // ---- fragment read addressing (swizzled) ----
  const int l15 = lane & 15;
  int kfrag[2];
#pragma unroll
  for (int ks = 0; ks < 2; ++ks)
    kfrag[ks] = ((ks * 64 + (lane >> 4) * 16) ^ ((lane & 7) << 4)) >> 1;
  const int arow = wm * 128 + l15;
  const int brow = wn * 64 + l15;

  f32x4 acc[8][4] = {};
  short8 bfr[4][2];

  // ---- prologue: stage tile 0 into buf 0; order B0..B3, A0, A2, A1, A3 ----
#pragma unroll
  for (int g = 0; g < 4; ++g)
    gload_lds16(pB + (size_t)g * 64 * KD, &sB[0][g * 4096 + ldst]);
  gload_lds16(pA + (size_t)0 * 64 * KD, &sA[0][0 * 4096 + ldst]);
  gload_lds16(pA + (size_t)2 * 64 * KD, &sA[0][2 * 4096 + ldst]);
  gload_lds16(pA + (size_t)1 * 64 * KD, &sA[0][1 * 4096 + ldst]);
  gload_lds16(pA + (size_t)3 * 64 * KD, &sA[0][3 * 4096 + ldst]);
  asm volatile("s_waitcnt vmcnt(2)" ::: "memory");
  __builtin_amdgcn_s_barrier();

  for (int t = 0; t < NT; ++t) {
    const int c  = t & 1;
    const int cn = c ^ 1;
    const int ktn = (t + 1 < NT) ? (t + 1) * BK : 0;   // wrapped: harmless dead loads on last tile
    const unsigned short* sAc = &sA[c][0];
    const unsigned short* sBc = &sB[c][0];

#pragma unroll
    for (int p = 0; p < 4; ++p) {
      // ds_read: this phase's A frags (4 x b128), + all B frags at p0 (8 x b128)
      short8 af[2][2];
#pragma unroll
      for (int i = 0; i < 2; ++i)
#pragma unroll
        for (int ks = 0; ks < 2; ++ks)
          af[i][ks] = *reinterpret_cast<const short8*>(
              sAc + (arow + (2 * p + i) * 16) * 64 + kfrag[ks]);
      if (p == 0) {
#pragma unroll
        for (int nf = 0; nf < 4; ++nf)
#pragma unroll
          for (int ks = 0; ks < 2; ++ks)
            bfr[nf][ks] = *reinterpret_cast<const short8*>(
                sBc + (brow + nf * 16) * 64 + kfrag[ks]);
      }

      // stage next K-tile: 2 loads/phase, stream B01 | B23 | A02 | A13
      if (p == 0) {
        gload_lds16(pB + (size_t)0 * 64 * KD + ktn, &sB[cn][0 * 4096 + ldst]);
        gload_lds16(pB + (size_t)1 * 64 * KD + ktn, &sB[cn][1 * 4096 + ldst]);
      } else if (p == 1) {
        gload_lds16(pB + (size_t)2 * 64 * KD + ktn, &sB[cn][2 * 4096 + ldst]);
        gload_lds16(pB + (size_t)3 * 64 * KD + ktn, &sB[cn][3 * 4096 + ldst]);
      } else if (p == 2) {
        gload_lds16(pA + (size_t)0 * 64 * KD + ktn, &sA[cn][0 * 4096 + ldst]);
        gload_lds16(pA + (size_t)2 * 64 * KD + ktn, &sA[cn][2 * 4096 + ldst]);
      } else {
        gload_lds16(pA + (size_t)1 * 64 * KD + ktn, &sA[cn][1 * 4096 + ldst]);
        gload_lds16(pA + (size_t)3 * 64 * KD + ktn, &sA[cn][3 * 4096 + ldst]);
      }

      __builtin_amdgcn_s_barrier();
      asm volatile("s_waitcnt lgkmcnt(0)" ::: "memory");
      __builtin_amdgcn_s_setprio(1);
#pragma unroll
      for (int i = 0; i < 2; ++i)
#pragma unroll
        for (int nf = 0; nf < 4; ++nf)
#pragma unroll
          for (int ks = 0; ks < 2; ++ks)
            acc[2 * p + i][nf] = __builtin_amdgcn_mfma_f32_16x16x32_bf16(
                af[i][ks], bfr[nf][ks], acc[2 * p + i][nf], 0, 0, 0);
      __builtin_amdgcn_s_setprio(0);
      // counted vmcnt (never 0): publish via the closing barrier
      if (p == 1) asm volatile("s_waitcnt vmcnt(4)" ::: "memory");
      if (p == 3) asm volatile("s_waitcnt vmcnt(2)" ::: "memory");
      __builtin_amdgcn_s_barrier();
    }
  }

  // ---- epilogue: K-split accumulate via device-scope atomics (d_out pre-zeroed) ----
  const int crow = m0 + wm * 128 + (lane >> 4) * 4;
  const int ccol = n0 + wn * 64 + l15;
#pragma unroll
  for (int mf = 0; mf < 8; ++mf)
#pragma unroll
    for (int nf = 0; nf < 4; ++nf)
#pragma unroll
      for (int j = 0; j < 4; ++j)
        atomicAdd(&C[(size_t)(crow + mf * 16 + j) * OUT_F + ccol + nf * 16],
                  acc[mf][nf][j]);
}

// ---------------- fallback (no workspace): direct f32 evaluation ----------------
__global__ __launch_bounds__(256) void naive_kernel(const float* __restrict__ x,
                                                    const float* __restrict__ a,
                                                    const float* __restrict__ b,
                                                    float* __restrict__ y) {
  int o  = blockIdx.x * 256 + threadIdx.x;
  int bb = blockIdx.y;
  __shared__ float xs[IN_F];
  for (int i = threadIdx.x; i < IN_F; i += 256) xs[i] = x[(size_t)bb * IN_F + i];
  __syncthreads();
  float acc = 0.f;
  for (int i = 0; i < IN_F; ++i) {
    float s1, c1; sincosf(xs[i], &s1, &c1);
    float sk = 0.f, ck = 1.f;
    const float* ap = a + (size_t)o * HALF_KD + i * KF;
    const float* bp = b + (size_t)o * HALF_KD + i * KF;
#pragma unroll
    for (int k = 0; k < KF; ++k) {
      acc += sk * ap[k] + ck * bp[k];
      float sn = sk * c1 + ck * s1;
      ck = ck * c1 - sk * s1;
      sk = sn;
    }
  }
  y[(size_t)bb * OUT_F + o] = acc;
}

extern "C" void kernel_launch(void* const* d_in, const int* in_sizes, int n_in,
                              void* d_out, int out_size, void* d_ws, size_t ws_size,
                              hipStream_t stream) {
  (void)in_sizes; (void)n_in; (void)out_size;
  const float* x = (const float*)d_in[0];
  const float* a = (const float*)d_in[1];
  const float* b = (const float*)d_in[2];
  float* y = (float*)d_out;

  const size_t XF_BYTES = (size_t)BATCH * KD * sizeof(unsigned short);   // 128 MiB
  const size_t W_BYTES  = (size_t)OUT_F * KD * sizeof(unsigned short);   // 32 MiB

  if (ws_size >= XF_BYTES + W_BYTES) {
    unsigned short* Xf = (unsigned short*)d_ws;
    unsigned short* W  = (unsigned short*)((char*)d_ws + XF_BYTES);
    hipMemsetAsync(d_out, 0, (size_t)BATCH * OUT_F * sizeof(float), stream);
    wconv_kernel<<<(OUT_F * KD / 8) / 256, 256, 0, stream>>>(a, b, W);
    feat_kernel<<<(BATCH * IN_F) / 256, 256, 0, stream>>>(x, Xf);
    gemm_kernel<<<dim3((BATCH / BM) * (OUT_F / BN) * KSPLIT), 512, 0, stream>>>(Xf, W, y);
  } else {
    naive_kernel<<<dim3(OUT_F / 256, BATCH), 256, 0, stream>>>(x, a, b, y);
  }
}

// Round 3
// 182.300 us; speedup vs baseline: 1.3311x; 1.0969x over previous
//
#include <hip/hip_runtime.h>

#define BATCH   4096
#define IN_F    1024
#define OUT_F   1024
#define KF      8
#define KD      (2*IN_F*KF)   /* 16384 GEMM K-dim */
#define HALF_KD (IN_F*KF)     /* 8192 */

#define BM 256
#define BN 256
#define BK 64
#define KSPLIT 4
#define KCHUNK (KD/KSPLIT)    /* 4096 */
#define NT (KCHUNK/BK)        /* 64 K-tiles per block */
#define C_ELEMS ((size_t)BATCH * OUT_F)

typedef short short8 __attribute__((ext_vector_type(8)));
typedef float f32x4  __attribute__((ext_vector_type(4)));

// bf16 round-to-nearest-even from f32 (bit pattern in ushort)
__device__ __forceinline__ unsigned short f2bf(float f) {
  union { float f; unsigned int u; } v; v.f = f;
  unsigned int u = v.u;
  unsigned int lsb = (u >> 16) & 1u;
  u += 0x7fffu + lsb;
  return (unsigned short)(u >> 16);
}

__device__ __forceinline__ void gload_lds16(const void* g, void* l) {
  __builtin_amdgcn_global_load_lds((const __attribute__((address_space(1))) void*)g,
                                   (__attribute__((address_space(3))) void*)l,
                                   16, 0, 0);
}

// ---------------- W conversion: [a | b] f32 -> bf16 [OUT_F][KD] ----------------
__global__ __launch_bounds__(256) void wconv_kernel(const float* __restrict__ a,
                                                    const float* __restrict__ b,
                                                    unsigned short* __restrict__ W) {
  size_t t = (size_t)blockIdx.x * 256 + threadIdx.x;
  size_t g = t * 8;
  int o = (int)(g >> 14);
  int f = (int)(g & (KD - 1));
  const float* src = (f < HALF_KD) ? (a + (size_t)o * HALF_KD + f)
                                   : (b + (size_t)o * HALF_KD + (f - HALF_KD));
  float4 v0 = reinterpret_cast<const float4*>(src)[0];
  float4 v1 = reinterpret_cast<const float4*>(src)[1];
  union { unsigned short h[8]; int4 v; } u;
  u.h[0] = f2bf(v0.x); u.h[1] = f2bf(v0.y); u.h[2] = f2bf(v0.z); u.h[3] = f2bf(v0.w);
  u.h[4] = f2bf(v1.x); u.h[5] = f2bf(v1.y); u.h[6] = f2bf(v1.z); u.h[7] = f2bf(v1.w);
  *reinterpret_cast<int4*>(W + g) = u.v;
}

// ---------------- feature kernel: Xf[b, i*8+k] = sin(k x), +8192 -> cos ----------------
__global__ __launch_bounds__(256) void feat_kernel(const float* __restrict__ x,
                                                   unsigned short* __restrict__ Xf) {
  int idx = blockIdx.x * 256 + threadIdx.x;
  int bb = idx >> 10;
  int i  = idx & 1023;
  float xv = x[idx];
  float s1, c1;
  sincosf(xv, &s1, &c1);
  float sv[KF], cv[KF];
  sv[0] = 0.f; cv[0] = 1.f;
  sv[1] = s1;  cv[1] = c1;
#pragma unroll
  for (int k = 2; k < KF; ++k) {
    sv[k] = sv[k-1]*c1 + cv[k-1]*s1;
    cv[k] = cv[k-1]*c1 - sv[k-1]*s1;
  }
  union { unsigned short h[8]; int4 v; } us, uc;
#pragma unroll
  for (int k = 0; k < KF; ++k) { us.h[k] = f2bf(sv[k]); uc.h[k] = f2bf(cv[k]); }
  size_t base = (size_t)bb * KD + (size_t)i * KF;
  *reinterpret_cast<int4*>(Xf + base)           = us.v;
  *reinterpret_cast<int4*>(Xf + base + HALF_KD) = uc.v;
}

// ---------------- GEMM: 256x256 tile, 8 waves, counted-vmcnt pipeline ----------------
// Per-wave 128x64 output = acc[8][4]; 4 phases/K-tile, 16 MFMA each; B-frags in regs.
// Staging: B-groups burst at p0, A-groups at p1 (3-5 phase lead on every load).
// Waits: vmcnt(8)@p1-end (retires prev A13), vmcnt(2)@p3-end (retires B+A02).
// T2 XOR swizzle via pre-swizzled global source + swizzled ds_read (0 conflicts, R2).
// Epilogue: plain stores to K-split slab (use_slab) or atomicAdd fallback.
__global__ __launch_bounds__(512, 2) void gemm_kernel(const unsigned short* __restrict__ A,
                                                      const unsigned short* __restrict__ Bt,
                                                      float* __restrict__ Cout,
                                                      int use_slab) {
  __shared__ unsigned short sA[2][BM * BK];   // 32 KiB each
  __shared__ unsigned short sB[2][BN * BK];

  const int tid  = threadIdx.x;
  const int wid  = tid >> 6;
  const int lane = tid & 63;
  const int wm = wid >> 2, wn = wid & 3;

  // bijective XCD swizzle: 256 blocks % 8 XCDs == 0; 32 consecutive work items/XCD
  const int bid = blockIdx.x;
  const int s   = (bid & 7) * 32 + (bid >> 3);
  const int z   = s >> 6;          // K-split chunk 0..3 (2 XCDs per chunk)
  const int mt  = s & 15;          // m-tile fastest -> XCD shares W panels in L2
  const int nt  = (s >> 4) & 3;
  const int m0  = mt * BM;
  const int n0  = nt * BN;
  const int fbase = z * KCHUNK;

  // ---- staging addressing (pre-swizzled global source, linear LDS dest) ----
  const int srow = wid * 8 + (lane >> 3);        // row within a 64-row group
  const int gsw  = (lane & 7) ^ (lane >> 3);     // swizzled 16B granule (involution)
  const unsigned short* pA = A  + (size_t)(m0 + srow) * KD + fbase + gsw * 8;
  const unsigned short* pB = Bt + (size_t)(n0 + srow) * KD + fbase + gsw * 8;
  const int ldst = wid * 512;                    // wave-uniform LDS elem offset in group

  // ---- fragment read addressing (swizzled) ----
  const int l15 = lane & 15;
  int kfrag[2];
#pragma unroll
  for (int ks = 0; ks < 2; ++ks)
    kfrag[ks] = ((ks * 64 + (lane >> 4) * 16) ^ ((lane & 7) << 4)) >> 1;
  const int arow = wm * 128 + l15;
  const int brow = wn * 64 + l15;

  f32x4 acc[8][4] = {};
  short8 bfr[4][2];

  // ---- prologue: stage tile 0 into buf 0 (retire order: B0..B3,A0,A2 then A1,A3) ----
#pragma unroll
  for (int g = 0; g < 4; ++g)
    gload_lds16(pB + (size_t)g * 64 * KD, &sB[0][g * 4096 + ldst]);
  gload_lds16(pA + (size_t)0 * 64 * KD, &sA[0][0 * 4096 + ldst]);
  gload_lds16(pA + (size_t)2 * 64 * KD, &sA[0][2 * 4096 + ldst]);
  gload_lds16(pA + (size_t)1 * 64 * KD, &sA[0][1 * 4096 + ldst]);
  gload_lds16(pA + (size_t)3 * 64 * KD, &sA[0][3 * 4096 + ldst]);
  asm volatile("s_waitcnt vmcnt(2)" ::: "memory");
  __builtin_amdgcn_s_barrier();

  for (int t = 0; t < NT; ++t) {
    const int c  = t & 1;
    const int cn = c ^ 1;
    const int ktn = (t + 1 < NT) ? (t + 1) * BK : 0;   // wrapped dead loads on last tile keep vmcnt ledger exact
    const unsigned short* sAc = &sA[c][0];
    const unsigned short* sBc = &sB[c][0];

#pragma unroll
    for (int p = 0; p < 4; ++p) {
      // ds_read: this phase's A frags (4 x b128), + all B frags at p0 (8 x b128)
      short8 af[2][2];
#pragma unroll
      for (int i = 0; i < 2; ++i)
#pragma unroll
        for (int ks = 0; ks < 2; ++ks)
          af[i][ks] = *reinterpret_cast<const short8*>(
              sAc + (arow + (2 * p + i) * 16) * 64 + kfrag[ks]);
      if (p == 0) {
#pragma unroll
        for (int nf = 0; nf < 4; ++nf)
#pragma unroll
          for (int ks = 0; ks < 2; ++ks)
            bfr[nf][ks] = *reinterpret_cast<const short8*>(
                sBc + (brow + nf * 16) * 64 + kfrag[ks]);
      }

      // stage next K-tile: B-groups at p0, A-groups at p1 (3-5 phase lead)
      if (p == 0) {
        gload_lds16(pB + (size_t)0 * 64 * KD + ktn, &sB[cn][0 * 4096 + ldst]);
        gload_lds16(pB + (size_t)1 * 64 * KD + ktn, &sB[cn][1 * 4096 + ldst]);
        gload_lds16(pB + (size_t)2 * 64 * KD + ktn, &sB[cn][2 * 4096 + ldst]);
        gload_lds16(pB + (size_t)3 * 64 * KD + ktn, &sB[cn][3 * 4096 + ldst]);
      } else if (p == 1) {
        gload_lds16(pA + (size_t)0 * 64 * KD + ktn, &sA[cn][0 * 4096 + ldst]);
        gload_lds16(pA + (size_t)2 * 64 * KD + ktn, &sA[cn][2 * 4096 + ldst]);
        gload_lds16(pA + (size_t)1 * 64 * KD + ktn, &sA[cn][1 * 4096 + ldst]);
        gload_lds16(pA + (size_t)3 * 64 * KD + ktn, &sA[cn][3 * 4096 + ldst]);
      }

      __builtin_amdgcn_s_barrier();
      asm volatile("s_waitcnt lgkmcnt(0)" ::: "memory");
      __builtin_amdgcn_s_setprio(1);
#pragma unroll
      for (int i = 0; i < 2; ++i)
#pragma unroll
        for (int nf = 0; nf < 4; ++nf)
#pragma unroll
          for (int ks = 0; ks < 2; ++ks)
            acc[2 * p + i][nf] = __builtin_amdgcn_mfma_f32_16x16x32_bf16(
                af[i][ks], bfr[nf][ks], acc[2 * p + i][nf], 0, 0, 0);
      __builtin_amdgcn_s_setprio(0);
      // counted vmcnt (never 0): publish via the closing barrier
      if (p == 1) asm volatile("s_waitcnt vmcnt(8)" ::: "memory");  // retire prev tile's A1,A3
      if (p == 3) asm volatile("s_waitcnt vmcnt(2)" ::: "memory");  // retire B0..B3,A0,A2
      __builtin_amdgcn_s_barrier();
    }
  }

  // ---- epilogue ----
  const int crow = m0 + wm * 128 + (lane >> 4) * 4;
  const int ccol = n0 + wn * 64 + l15;
  if (use_slab) {
    float* Cz = Cout + (size_t)z * C_ELEMS;
#pragma unroll
    for (int mf = 0; mf < 8; ++mf)
#pragma unroll
      for (int nf = 0; nf < 4; ++nf)
#pragma unroll
        for (int j = 0; j < 4; ++j)
          Cz[(size_t)(crow + mf * 16 + j) * OUT_F + ccol + nf * 16] = acc[mf][nf][j];
  } else {
#pragma unroll
    for (int mf = 0; mf < 8; ++mf)
#pragma unroll
      for (int nf = 0; nf < 4; ++nf)
#pragma unroll
        for (int j = 0; j < 4; ++j)
          atomicAdd(&Cout[(size_t)(crow + mf * 16 + j) * OUT_F + ccol + nf * 16],
                    acc[mf][nf][j]);
  }
}

// ---------------- K-split slab reduce: y = s0+s1+s2+s3 (float4) ----------------
__global__ __launch_bounds__(256) void reduce_kernel(const f32x4* __restrict__ s,
                                                     f32x4* __restrict__ y) {
  size_t i = (size_t)blockIdx.x * 256 + threadIdx.x;
  const size_t NQ = C_ELEMS / 4;
  f32x4 v = s[i] + s[i + NQ] + s[i + 2 * NQ] + s[i + 3 * NQ];
  y[i] = v;
}

// ---------------- fallback (no workspace): direct f32 evaluation ----------------
__global__ __launch_bounds__(256) void naive_kernel(const float* __restrict__ x,
                                                    const float* __restrict__ a,
                                                    const float* __restrict__ b,
                                                    float* __restrict__ y) {
  int o  = blockIdx.x * 256 + threadIdx.x;
  int bb = blockIdx.y;
  __shared__ float xs[IN_F];
  for (int i = threadIdx.x; i < IN_F; i += 256) xs[i] = x[(size_t)bb * IN_F + i];
  __syncthreads();
  float acc = 0.f;
  for (int i = 0; i < IN_F; ++i) {
    float s1, c1; sincosf(xs[i], &s1, &c1);
    float sk = 0.f, ck = 1.f;
    const float* ap = a + (size_t)o * HALF_KD + i * KF;
    const float* bp = b + (size_t)o * HALF_KD + i * KF;
#pragma unroll
    for (int k = 0; k < KF; ++k) {
      acc += sk * ap[k] + ck * bp[k];
      float sn = sk * c1 + ck * s1;
      ck = ck * c1 - sk * s1;
      sk = sn;
    }
  }
  y[(size_t)bb * OUT_F + o] = acc;
}

extern "C" void kernel_launch(void* const* d_in, const int* in_sizes, int n_in,
                              void* d_out, int out_size, void* d_ws, size_t ws_size,
                              hipStream_t stream) {
  (void)in_sizes; (void)n_in; (void)out_size;
  const float* x = (const float*)d_in[0];
  const float* a = (const float*)d_in[1];
  const float* b = (const float*)d_in[2];
  float* y = (float*)d_out;

  const size_t XF_BYTES   = (size_t)BATCH * KD * sizeof(unsigned short);   // 128 MiB
  const size_t W_BYTES    = (size_t)OUT_F * KD * sizeof(unsigned short);   // 32 MiB
  const size_t SLAB_BYTES = C_ELEMS * sizeof(float) * KSPLIT;              // 64 MiB

  if (ws_size >= XF_BYTES + W_BYTES) {
    unsigned short* Xf = (unsigned short*)d_ws;
    unsigned short* W  = (unsigned short*)((char*)d_ws + XF_BYTES);
    const bool slab = ws_size >= XF_BYTES + W_BYTES + SLAB_BYTES;
    float* slabs = (float*)((char*)d_ws + XF_BYTES + W_BYTES);

    wconv_kernel<<<(OUT_F * KD / 8) / 256, 256, 0, stream>>>(a, b, W);
    feat_kernel<<<(BATCH * IN_F) / 256, 256, 0, stream>>>(x, Xf);
    if (slab) {
      gemm_kernel<<<dim3((BATCH / BM) * (OUT_F / BN) * KSPLIT), 512, 0, stream>>>(Xf, W, slabs, 1);
      reduce_kernel<<<(int)(C_ELEMS / 4 / 256), 256, 0, stream>>>((const f32x4*)slabs, (f32x4*)y);
    } else {
      hipMemsetAsync(d_out, 0, C_ELEMS * sizeof(float), stream);
      gemm_kernel<<<dim3((BATCH / BM) * (OUT_F / BN) * KSPLIT), 512, 0, stream>>>(Xf, W, y, 0);
    }
  } else {
    naive_kernel<<<dim3(OUT_F / 256, BATCH), 256, 0, stream>>>(x, a, b, y);
  }
}